// Round 11
// baseline (372.680 us; speedup 1.0000x reference)
//
#include <hip/hip_runtime.h>

#define BATCH 8
#define DIM 192
#define HH 128
#define WW 128
#define KS 7
#define PAD 3
#define HID 48
#define KK 49            // KS*KS
#define BN_EPS 1e-5f

#define TILE_H 32
#define NTILE (HH / TILE_H)          // 4
#define RPT   4                      // output rows per thread (8 strips x 4 rows)

// ---------------- Kernel A: global average pool over H*W ----------------
__global__ __launch_bounds__(256) void pool_kernel(const float* __restrict__ x,
                                                   float* __restrict__ pooled) {
    const int bc = blockIdx.x;                       // 0..B*DIM-1
    const float4* p = (const float4*)(x + (size_t)bc * HH * WW);
    const int t = threadIdx.x;
    float s = 0.f;
#pragma unroll
    for (int i = 0; i < 16; ++i) {                   // 16384 floats = 4096 float4 / 256 thr
        float4 v = p[t + i * 256];
        s += (v.x + v.y) + (v.z + v.w);
    }
#pragma unroll
    for (int off = 32; off > 0; off >>= 1) s += __shfl_down(s, off, 64);
    __shared__ float wsum[4];
    const int wave = t >> 6, lane = t & 63;
    if (lane == 0) wsum[wave] = s;
    __syncthreads();
    if (t == 0) {
        float tot = (wsum[0] + wsum[1]) + (wsum[2] + wsum[3]);
        pooled[bc] = tot * (1.0f / (HH * WW));
    }
}

// ---------------- Kernel B: fused weight-gen + depthwise 7x7 conv ----------
// R10/R11: x-LDS staging REMOVED (m169 lesson: don't stage cache-fit data).
// Evidence: R8 (no tile loop, 16 waves/CU) == R9 (dbuf pipeline, 12 waves/CU)
// == 91.4us -> the shared staging pipeline (DMA + vmcnt(0) barrier drains +
// ds_read_b128 inner loop on one LDS unit/CU) is the limiter, not residency
// or wgen. FETCH 53MB < x's 100MB compulsory proves x is L3-resident after
// pool_kernel -> the 49x stencil reuse is served by L1/L2/L3 directly.
// The compute loop below produces byte-identical v-values in the identical
// FMA order as the R6/R8/R9-verified kernels; only the source of v changes
// (3 predicated global float4 loads per input row, coalesced, L3-hot).
// LDS shrinks to y_s+wk_s (~400B). No launch-bounds 2nd arg (toolchain
// poison: R2 correctness, R6 64-VGPR spill disaster).
__global__ __launch_bounds__(256) void dwconv_fused_kernel(
        const float* __restrict__ x,
        const float* __restrict__ pooled,
        const float* __restrict__ w1,
        const float* __restrict__ gamma,
        const float* __restrict__ beta,
        const float* __restrict__ mean,
        const float* __restrict__ var,
        const float* __restrict__ w2,
        const float* __restrict__ b2,
        const float* __restrict__ bias,
        float* __restrict__ out) {
    __shared__ float y_s[HID];
    __shared__ float wk_s[KK];
    const int tile = blockIdx.x & (NTILE - 1);       // tiles of a channel adjacent
    const int bc = blockIdx.x >> 2;
    const int b = bc / DIM;
    const int c = bc % DIM;
    const int t = threadIdx.x;
    const int r0 = tile * TILE_H;

    // ---- inline weight generation, stage 1: y = relu(BN(pooled[b] @ w1^T)) ----
    if (t < HID) {
        const float4* pr = (const float4*)(pooled + b * DIM);
        const float4* wr = (const float4*)(w1 + (size_t)t * DIM);
        float acc = 0.f;
#pragma unroll
        for (int j = 0; j < DIM / 4; ++j) {
            float4 pv = pr[j], wv = wr[j];
            acc += pv.x * wv.x + pv.y * wv.y + pv.z * wv.z + pv.w * wv.w;
        }
        float yv = (acc - mean[t]) * rsqrtf(var[t] + BN_EPS) * gamma[t] + beta[t];
        y_s[t] = yv > 0.f ? yv : 0.f;
    }
    __syncthreads();                                 // y_s visible

    // ---- stage 2: wk[k] = b2 + y . w2row ----
    if (t < KK) {
        const int o = c * KK + t;
        const float4* w2r = (const float4*)(w2 + (size_t)o * HID);
        float acc = b2[o];
#pragma unroll
        for (int j = 0; j < HID / 4; ++j) {
            float4 wv = w2r[j];
            acc += y_s[4 * j] * wv.x + y_s[4 * j + 1] * wv.y +
                   y_s[4 * j + 2] * wv.z + y_s[4 * j + 3] * wv.w;
        }
        wk_s[t] = acc;
    }
    __syncthreads();

    // ---- weights in VGPRs (R0/R8-proven form) ----
    float wreg[KK];
#pragma unroll
    for (int i = 0; i < KK; ++i) wreg[i] = wk_s[i];
    const float bv = bias[c];

    // ---- compute: 8 strips x 4 rows, sliding window over 10 input rows ----
    // v-values and FMA order identical to the verified LDS version; source
    // is now direct global (L3-hot). Row predicate is uniform per half-wave.
    const int c4 = t & 31;                           // 4-col group
    const int strip = t >> 5;                        // 0..7
    const int sbase = strip * RPT;
    const float* xchan = x + (size_t)bc * HH * WW;
    float* outp = out + (size_t)bc * HH * WW + (size_t)(r0 + sbase) * WW + c4 * 4;

    float acc[RPT][4];
#pragma unroll
    for (int i = 0; i < RPT; ++i)
        acc[i][0] = acc[i][1] = acc[i][2] = acc[i][3] = 0.f;

#pragma unroll
    for (int ir = 0; ir < RPT + KS - 1; ++ir) {      // 10 input rows
        const int gr = r0 + sbase + ir - PAD;        // global input row
        float4 f0 = make_float4(0.f, 0.f, 0.f, 0.f);
        float4 f1 = make_float4(0.f, 0.f, 0.f, 0.f);
        float4 f2 = make_float4(0.f, 0.f, 0.f, 0.f);
        if (gr >= 0 && gr < HH) {                    // image rows only (else zero pad)
            const float4* row4 = (const float4*)(xchan + (size_t)gr * WW);
            f1 = row4[c4];
            if (c4 > 0)  f0 = row4[c4 - 1];          // cols -4..-1 (zero at left edge)
            if (c4 < 31) f2 = row4[c4 + 1];          // cols +4..+7 (zero at right edge)
        }
        const float v[12] = {f0.x, f0.y, f0.z, f0.w,
                             f1.x, f1.y, f1.z, f1.w,
                             f2.x, f2.y, f2.z, f2.w};
#pragma unroll
        for (int ky = 0; ky < KS; ++ky) {
            const int o = ir - ky;                   // pending output row (compile-time)
            if (o >= 0 && o < RPT) {
                float* a = acc[o];
#pragma unroll
                for (int kx = 0; kx < KS; ++kx) {
                    const float wv = wreg[ky * KS + kx];
                    a[0] += wv * v[1 + kx];
                    a[1] += wv * v[2 + kx];
                    a[2] += wv * v[3 + kx];
                    a[3] += wv * v[4 + kx];
                }
            }
        }
        if (ir >= KS - 1) {                          // output row ir-6 complete
            float* a = acc[ir - (KS - 1)];
            float4 o4 = make_float4(a[0] + bv, a[1] + bv, a[2] + bv, a[3] + bv);
            *((float4*)(outp + (size_t)(ir - (KS - 1)) * WW)) = o4;
        }
    }
}

extern "C" void kernel_launch(void* const* d_in, const int* in_sizes, int n_in,
                              void* d_out, int out_size, void* d_ws, size_t ws_size,
                              hipStream_t stream) {
    const float* x     = (const float*)d_in[0];
    const float* w1    = (const float*)d_in[1];
    const float* gamma = (const float*)d_in[2];
    const float* beta  = (const float*)d_in[3];
    const float* mean  = (const float*)d_in[4];
    const float* var   = (const float*)d_in[5];
    const float* w2    = (const float*)d_in[6];
    const float* b2    = (const float*)d_in[7];
    const float* bias  = (const float*)d_in[8];
    float* out = (float*)d_out;

    float* pooled = (float*)d_ws;                    // B*DIM floats (6 KB, proven size)

    pool_kernel<<<BATCH * DIM, 256, 0, stream>>>(x, pooled);
    dwconv_fused_kernel<<<BATCH * DIM * NTILE, 256, 0, stream>>>(
        x, pooled, w1, gamma, beta, mean, var, w2, b2, bias, out);
}

// Round 12
// 237.693 us; speedup vs baseline: 1.5679x; 1.5679x over previous
//
#include <hip/hip_runtime.h>

#define BATCH 8
#define DIM 192
#define HH 128
#define WW 128
#define KS 7
#define PAD 3
#define HID 48
#define KK 49            // KS*KS
#define BN_EPS 1e-5f

#define TILE_H 32
#define SROWS (TILE_H + KS - 1)      // 38
#define NSLOT (SROWS * (WW / 4))     // 1216 float4 slots = 19*64 -> wave-uniform guard ok
#define NTILE (HH / TILE_H)          // 4
#define RPT   4                      // output rows per thread (8 strips x 4 rows)

static_assert(NSLOT % 64 == 0, "staging guard must be wave-uniform");

// ---------------- Kernel A: global average pool over H*W ----------------
__global__ __launch_bounds__(256) void pool_kernel(const float* __restrict__ x,
                                                   float* __restrict__ pooled) {
    const int bc = blockIdx.x;                       // 0..B*DIM-1
    const float4* p = (const float4*)(x + (size_t)bc * HH * WW);
    const int t = threadIdx.x;
    float s = 0.f;
#pragma unroll
    for (int i = 0; i < 16; ++i) {                   // 16384 floats = 4096 float4 / 256 thr
        float4 v = p[t + i * 256];
        s += (v.x + v.y) + (v.z + v.w);
    }
#pragma unroll
    for (int off = 32; off > 0; off >>= 1) s += __shfl_down(s, off, 64);
    __shared__ float wsum[4];
    const int wave = t >> 6, lane = t & 63;
    if (lane == 0) wsum[wave] = s;
    __syncthreads();
    if (t == 0) {
        float tot = (wsum[0] + wsum[1]) + (wsum[2] + wsum[3]);
        pooled[bc] = tot * (1.0f / (HH * WW));
    }
}

// ---------------- Kernel A2: per-batch y = relu(BN(pooled @ w1^T)) ----------
// y[b][0..47] is PER-BATCH (384 dots of 192 total) but was recomputed by all
// 6144 dwconv blocks (stage-1: 96 L2 loads by 48/1024 lanes while 3.8 waves
// idled at the barrier). Hoisting it removes the longest serial-latency
// phase from every dwconv block's prologue. Math identical to the verified
// inline stage-1.
__global__ __launch_bounds__(64) void wgen_y_kernel(
        const float* __restrict__ pooled,
        const float* __restrict__ w1,
        const float* __restrict__ gamma,
        const float* __restrict__ beta,
        const float* __restrict__ mean,
        const float* __restrict__ var,
        float* __restrict__ y_glob) {
    const int b = blockIdx.x;                        // 0..7
    const int t = threadIdx.x;
    if (t < HID) {
        const float4* pr = (const float4*)(pooled + b * DIM);
        const float4* wr = (const float4*)(w1 + (size_t)t * DIM);
        float acc = 0.f;
#pragma unroll
        for (int j = 0; j < DIM / 4; ++j) {
            float4 pv = pr[j], wv = wr[j];
            acc += pv.x * wv.x + pv.y * wv.y + pv.z * wv.z + pv.w * wv.w;
        }
        float yv = (acc - mean[t]) * rsqrtf(var[t] + BN_EPS) * gamma[t] + beta[t];
        y_glob[b * HID + t] = yv > 0.f ? yv : 0.f;
    }
}

// ---------------- Kernel B: fused weight-gen-2 + depthwise 7x7 conv --------
// R12: R8-proven kernel with stage-1 replaced by a 48-float y_glob load
// (computed once per batch by wgen_y_kernel). Stage-2 (49x48 dot, w2 rows
// L2-hot across the 32 blocks sharing channel c) stays inline -- NOT
// reviving R1's full wdyn hoist (320KB ws unexonerated; y needs 1.5KB,
// within the proven ws envelope). Compute loop/staging/zero-fill byte-
// identical to R8 (passed, absmax 9.8e-4, 91.4us).
// Evidence: R11 proved LDS staging REQUIRED (direct-global = 205us,
// latency-bound). R0~R8~R9 at ~90us regardless of tile/pipeline/wgen-
// redundancy -> remaining candidate is the phase-locked serial prologue.
// No launch-bounds 2nd arg (toolchain poison: R2 correctness, R6 spills).
__global__ __launch_bounds__(256) void dwconv_fused_kernel(
        const float* __restrict__ x,
        const float* __restrict__ y_glob,
        const float* __restrict__ w2,
        const float* __restrict__ b2,
        const float* __restrict__ bias,
        float* __restrict__ out) {
    __shared__ float smem[SROWS][WW];                // 38*128*4 = 19456 B
    __shared__ float y_s[HID];
    __shared__ float wk_s[KK];
    const int tile = blockIdx.x & (NTILE - 1);       // tiles of a channel adjacent
    const int bc = blockIdx.x >> 2;
    const int b = bc / DIM;
    const int c = bc % DIM;
    const int t = threadIdx.x;
    const int r0 = tile * TILE_H;

    // ---- issue async staging DMA first ----
    // valid input rows: [r0-3, r0+34] ∩ [0,128)
    const int slo = (tile == 0) ? PAD * (WW / 4) : 0;                       // 96 or 0
    const int shi = (tile == NTILE - 1) ? (SROWS - PAD) * (WW / 4) : NSLOT; // 1120 or 1216
    const float* xbase = x + (size_t)bc * HH * WW + (ptrdiff_t)(r0 - PAD) * WW;

#pragma unroll
    for (int i = 0; i < (NSLOT + 255) / 256; ++i) {  // 5 iters
        const int s = t + i * 256;
        if (s < NSLOT) {                             // wave-uniform (1216 = 19*64)
            int sc = s;                              // clamp SOURCE only (per-lane ok)
            if (sc < slo) sc = slo;
            if (sc >= shi) sc = shi - 1;
            __builtin_amdgcn_global_load_lds(
                (const __attribute__((address_space(1))) void*)(xbase + (size_t)sc * 4),
                (__attribute__((address_space(3))) void*)((float*)smem + (size_t)s * 4),
                16, 0, 0);
        }
    }

    // ---- stage 1 is now a single L2-hot load of the hoisted y ----
    if (t < HID) y_s[t] = y_glob[b * HID + t];
    __syncthreads();                                 // y_s visible; DMA drained

    // ---- stage 2: wk[k] = b2 + y . w2row   |   zero-fill 3 halo rows ----
    if (t < KK) {
        const int o = c * KK + t;
        const float4* w2r = (const float4*)(w2 + (size_t)o * HID);
        float acc = b2[o];
#pragma unroll
        for (int j = 0; j < HID / 4; ++j) {
            float4 wv = w2r[j];
            acc += y_s[4 * j] * wv.x + y_s[4 * j + 1] * wv.y +
                   y_s[4 * j + 2] * wv.z + y_s[4 * j + 3] * wv.w;
        }
        wk_s[t] = acc;
    } else if (t >= 160) {                           // 96 threads, 96 float4 slots
        const int zi = t - 160;
        if (tile == 0) {
            ((float4*)smem)[zi] = make_float4(0.f, 0.f, 0.f, 0.f);
        } else if (tile == NTILE - 1) {
            ((float4*)smem)[(SROWS - PAD) * (WW / 4) + zi] =
                make_float4(0.f, 0.f, 0.f, 0.f);
        }
    }
    __syncthreads();

    // ---- weights in VGPRs (R0/R8-proven form) ----
    float wreg[KK];
#pragma unroll
    for (int i = 0; i < KK; ++i) wreg[i] = wk_s[i];
    const float bv = bias[c];

    // ---- compute: 8 strips x 4 rows, sliding window over 10 input rows ----
    const int c4 = t & 31;                           // 4-col group
    const int strip = t >> 5;                        // 0..7
    const int sbase = strip * RPT;
    float* outp = out + (size_t)bc * HH * WW + (size_t)(r0 + sbase) * WW + c4 * 4;

    float acc[RPT][4];
#pragma unroll
    for (int i = 0; i < RPT; ++i)
        acc[i][0] = acc[i][1] = acc[i][2] = acc[i][3] = 0.f;

#pragma unroll
    for (int ir = 0; ir < RPT + KS - 1; ++ir) {      // 10 input rows
        const float4* row4 = (const float4*)&smem[sbase + ir][0];
        const float4 f1 = row4[c4];
        float4 f0 = make_float4(0.f, 0.f, 0.f, 0.f);
        float4 f2 = make_float4(0.f, 0.f, 0.f, 0.f);
        if (c4 > 0)  f0 = row4[c4 - 1];              // cols -4..-1 (zero at left edge)
        if (c4 < 31) f2 = row4[c4 + 1];              // cols +4..+7 (zero at right edge)
        const float v[12] = {f0.x, f0.y, f0.z, f0.w,
                             f1.x, f1.y, f1.z, f1.w,
                             f2.x, f2.y, f2.z, f2.w};
#pragma unroll
        for (int ky = 0; ky < KS; ++ky) {
            const int o = ir - ky;                   // pending output row (compile-time)
            if (o >= 0 && o < RPT) {
                float* a = acc[o];
#pragma unroll
                for (int kx = 0; kx < KS; ++kx) {
                    const float wv = wreg[ky * KS + kx];
                    a[0] += wv * v[1 + kx];
                    a[1] += wv * v[2 + kx];
                    a[2] += wv * v[3 + kx];
                    a[3] += wv * v[4 + kx];
                }
            }
        }
        if (ir >= KS - 1) {                          // output row ir-6 complete
            float* a = acc[ir - (KS - 1)];
            float4 o4 = make_float4(a[0] + bv, a[1] + bv, a[2] + bv, a[3] + bv);
            *((float4*)(outp + (size_t)(ir - (KS - 1)) * WW)) = o4;
        }
    }
}

extern "C" void kernel_launch(void* const* d_in, const int* in_sizes, int n_in,
                              void* d_out, int out_size, void* d_ws, size_t ws_size,
                              hipStream_t stream) {
    const float* x     = (const float*)d_in[0];
    const float* w1    = (const float*)d_in[1];
    const float* gamma = (const float*)d_in[2];
    const float* beta  = (const float*)d_in[3];
    const float* mean  = (const float*)d_in[4];
    const float* var   = (const float*)d_in[5];
    const float* w2    = (const float*)d_in[6];
    const float* b2    = (const float*)d_in[7];
    const float* bias  = (const float*)d_in[8];
    float* out = (float*)d_out;

    // workspace: pooled [1536] | y [384]  = 7.7 KB (proven envelope was 6 KB)
    float* pooled = (float*)d_ws;
    float* y_glob = pooled + BATCH * DIM;            // offset 6144 B, 16B-aligned

    pool_kernel<<<BATCH * DIM, 256, 0, stream>>>(x, pooled);
    wgen_y_kernel<<<BATCH, 64, 0, stream>>>(pooled, w1, gamma, beta, mean, var, y_glob);
    dwconv_fused_kernel<<<BATCH * DIM * NTILE, 256, 0, stream>>>(
        x, y_glob, w2, b2, bias, out);
}

// Round 13
// 235.095 us; speedup vs baseline: 1.5852x; 1.0111x over previous
//
#include <hip/hip_runtime.h>

#define BATCH 8
#define DIM 192
#define HH 128
#define WW 128
#define KS 7
#define PAD 3
#define HID 48
#define KK 49            // KS*KS
#define BN_EPS 1e-5f
#define WSTR 52          // wdyn row stride (floats): 208 B, keeps rows 16B-aligned

#define TILE_H 32
#define SROWS (TILE_H + KS - 1)      // 38
#define NSLOT (SROWS * (WW / 4))     // 1216 float4 slots = 19*64 -> wave-uniform guard ok
#define NTILE (HH / TILE_H)          // 4
#define RPT   4                      // output rows per thread (8 strips x 4 rows)

static_assert(NSLOT % 64 == 0, "staging guard must be wave-uniform");

// ---------------- Kernel A: global average pool over H*W ----------------
__global__ __launch_bounds__(256) void pool_kernel(const float* __restrict__ x,
                                                   float* __restrict__ pooled) {
    const int bc = blockIdx.x;                       // 0..B*DIM-1
    const float4* p = (const float4*)(x + (size_t)bc * HH * WW);
    const int t = threadIdx.x;
    float s = 0.f;
#pragma unroll
    for (int i = 0; i < 16; ++i) {                   // 16384 floats = 4096 float4 / 256 thr
        float4 v = p[t + i * 256];
        s += (v.x + v.y) + (v.z + v.w);
    }
#pragma unroll
    for (int off = 32; off > 0; off >>= 1) s += __shfl_down(s, off, 64);
    __shared__ float wsum[4];
    const int wave = t >> 6, lane = t & 63;
    if (lane == 0) wsum[wave] = s;
    __syncthreads();
    if (t == 0) {
        float tot = (wsum[0] + wsum[1]) + (wsum[2] + wsum[3]);
        pooled[bc] = tot * (1.0f / (HH * WW));
    }
}

// ------------- Kernel A2 (hoist path): full weight-gen per (b,c) -----------
// One 64-thread block per channel: y[b] computed redundantly (48 thr x
// 192-dot, pooled/w1 L2-hot -- same math as the R12-proven stages), then 49
// thr x 48-dot -> wdyn row. R1/R2's 2e-2 failures shared only the
// readfirstlane weight path (R2 had NO workspace); wdyn itself is innocent.
__global__ __launch_bounds__(64) void wgen_full_kernel(
        const float* __restrict__ pooled,
        const float* __restrict__ w1,
        const float* __restrict__ gamma,
        const float* __restrict__ beta,
        const float* __restrict__ mean,
        const float* __restrict__ var,
        const float* __restrict__ w2,
        const float* __restrict__ b2,
        float* __restrict__ wdyn) {
    __shared__ float y_s[HID];
    const int bc = blockIdx.x;
    const int b = bc / DIM, c = bc % DIM;
    const int t = threadIdx.x;
    if (t < HID) {
        const float4* pr = (const float4*)(pooled + b * DIM);
        const float4* wr = (const float4*)(w1 + (size_t)t * DIM);
        float acc = 0.f;
#pragma unroll
        for (int j = 0; j < DIM / 4; ++j) {
            float4 pv = pr[j], wv = wr[j];
            acc += pv.x * wv.x + pv.y * wv.y + pv.z * wv.z + pv.w * wv.w;
        }
        float yv = (acc - mean[t]) * rsqrtf(var[t] + BN_EPS) * gamma[t] + beta[t];
        y_s[t] = yv > 0.f ? yv : 0.f;
    }
    __syncthreads();
    if (t < KK) {
        const int o = c * KK + t;
        const float4* w2r = (const float4*)(w2 + (size_t)o * HID);
        float acc = b2[o];
#pragma unroll
        for (int j = 0; j < HID / 4; ++j) {
            float4 wv = w2r[j];
            acc += y_s[4 * j] * wv.x + y_s[4 * j + 1] * wv.y +
                   y_s[4 * j + 2] * wv.z + y_s[4 * j + 3] * wv.w;
        }
        wdyn[(size_t)bc * WSTR + t] = acc;
    }
}

// ------------- Kernel A2 (fallback path): per-batch y only (R12) -----------
__global__ __launch_bounds__(64) void wgen_y_kernel(
        const float* __restrict__ pooled,
        const float* __restrict__ w1,
        const float* __restrict__ gamma,
        const float* __restrict__ beta,
        const float* __restrict__ mean,
        const float* __restrict__ var,
        float* __restrict__ y_glob) {
    const int b = blockIdx.x;                        // 0..7
    const int t = threadIdx.x;
    if (t < HID) {
        const float4* pr = (const float4*)(pooled + b * DIM);
        const float4* wr = (const float4*)(w1 + (size_t)t * DIM);
        float acc = 0.f;
#pragma unroll
        for (int j = 0; j < DIM / 4; ++j) {
            float4 pv = pr[j], wv = wr[j];
            acc += pv.x * wv.x + pv.y * wv.y + pv.z * wv.z + pv.w * wv.w;
        }
        float yv = (acc - mean[t]) * rsqrtf(var[t] + BN_EPS) * gamma[t] + beta[t];
        y_glob[b * HID + t] = yv > 0.f ? yv : 0.f;
    }
}

// ---------- Kernel B (hoist path): depthwise 7x7, weights preloaded --------
// R13: stage-2 replaced by one L2-hot row load issued under the in-flight
// DMA; weights stay in VGPRs (proven form, NO readfirstlane). Middle tiles
// need only ONE barrier; edge tiles zero-fill after the drain barrier
// (block-uniform condition -> conditional barrier legal). Staging and
// compute loop byte-identical to R12 (passed, absmax 9.8e-4, 65.5us).
// No launch-bounds 2nd arg (toolchain poison: R2 correctness, R6 spills).
__global__ __launch_bounds__(256) void dwconv_hoisted_kernel(
        const float* __restrict__ x,
        const float* __restrict__ wdyn,
        const float* __restrict__ bias,
        float* __restrict__ out) {
    __shared__ float smem[SROWS][WW];                // 38*128*4 = 19456 B
    __shared__ float wk_s[KK];
    const int tile = blockIdx.x & (NTILE - 1);       // tiles of a channel adjacent
    const int bc = blockIdx.x >> 2;
    const int c = bc % DIM;
    const int t = threadIdx.x;
    const int r0 = tile * TILE_H;

    // ---- issue async staging DMA first ----
    const int slo = (tile == 0) ? PAD * (WW / 4) : 0;                       // 96 or 0
    const int shi = (tile == NTILE - 1) ? (SROWS - PAD) * (WW / 4) : NSLOT; // 1120 or 1216
    const float* xbase = x + (size_t)bc * HH * WW + (ptrdiff_t)(r0 - PAD) * WW;

#pragma unroll
    for (int i = 0; i < (NSLOT + 255) / 256; ++i) {  // 5 iters
        const int s = t + i * 256;
        if (s < NSLOT) {                             // wave-uniform (1216 = 19*64)
            int sc = s;                              // clamp SOURCE only (per-lane ok)
            if (sc < slo) sc = slo;
            if (sc >= shi) sc = shi - 1;
            __builtin_amdgcn_global_load_lds(
                (const __attribute__((address_space(1))) void*)(xbase + (size_t)sc * 4),
                (__attribute__((address_space(3))) void*)((float*)smem + (size_t)s * 4),
                16, 0, 0);
        }
    }

    // ---- preloaded weights: one L2-hot load, overlaps in-flight DMA ----
    if (t < KK) wk_s[t] = wdyn[(size_t)bc * WSTR + t];
    __syncthreads();                                 // DMA drained; wk_s visible

    // ---- zero-fill halo rows (edge tiles only; block-uniform barrier) ----
    if (tile == 0) {
        if (t < 96) ((float4*)smem)[t] = make_float4(0.f, 0.f, 0.f, 0.f);
        __syncthreads();
    } else if (tile == NTILE - 1) {
        if (t < 96)
            ((float4*)smem)[(SROWS - PAD) * (WW / 4) + t] =
                make_float4(0.f, 0.f, 0.f, 0.f);
        __syncthreads();
    }

    // ---- weights in VGPRs (proven form) ----
    float wreg[KK];
#pragma unroll
    for (int i = 0; i < KK; ++i) wreg[i] = wk_s[i];
    const float bv = bias[c];

    // ---- compute: 8 strips x 4 rows, sliding window over 10 input rows ----
    const int c4 = t & 31;                           // 4-col group
    const int strip = t >> 5;                        // 0..7
    const int sbase = strip * RPT;
    float* outp = out + (size_t)bc * HH * WW + (size_t)(r0 + sbase) * WW + c4 * 4;

    float acc[RPT][4];
#pragma unroll
    for (int i = 0; i < RPT; ++i)
        acc[i][0] = acc[i][1] = acc[i][2] = acc[i][3] = 0.f;

#pragma unroll
    for (int ir = 0; ir < RPT + KS - 1; ++ir) {      // 10 input rows
        const float4* row4 = (const float4*)&smem[sbase + ir][0];
        const float4 f1 = row4[c4];
        float4 f0 = make_float4(0.f, 0.f, 0.f, 0.f);
        float4 f2 = make_float4(0.f, 0.f, 0.f, 0.f);
        if (c4 > 0)  f0 = row4[c4 - 1];              // cols -4..-1 (zero at left edge)
        if (c4 < 31) f2 = row4[c4 + 1];              // cols +4..+7 (zero at right edge)
        const float v[12] = {f0.x, f0.y, f0.z, f0.w,
                             f1.x, f1.y, f1.z, f1.w,
                             f2.x, f2.y, f2.z, f2.w};
#pragma unroll
        for (int ky = 0; ky < KS; ++ky) {
            const int o = ir - ky;                   // pending output row (compile-time)
            if (o >= 0 && o < RPT) {
                float* a = acc[o];
#pragma unroll
                for (int kx = 0; kx < KS; ++kx) {
                    const float wv = wreg[ky * KS + kx];
                    a[0] += wv * v[1 + kx];
                    a[1] += wv * v[2 + kx];
                    a[2] += wv * v[3 + kx];
                    a[3] += wv * v[4 + kx];
                }
            }
        }
        if (ir >= KS - 1) {                          // output row ir-6 complete
            float* a = acc[ir - (KS - 1)];
            float4 o4 = make_float4(a[0] + bv, a[1] + bv, a[2] + bv, a[3] + bv);
            *((float4*)(outp + (size_t)(ir - (KS - 1)) * WW)) = o4;
        }
    }
}

// ---------- Kernel B (fallback path): R12 kernel, verbatim -----------------
__global__ __launch_bounds__(256) void dwconv_fused_kernel(
        const float* __restrict__ x,
        const float* __restrict__ y_glob,
        const float* __restrict__ w2,
        const float* __restrict__ b2,
        const float* __restrict__ bias,
        float* __restrict__ out) {
    __shared__ float smem[SROWS][WW];                // 38*128*4 = 19456 B
    __shared__ float y_s[HID];
    __shared__ float wk_s[KK];
    const int tile = blockIdx.x & (NTILE - 1);
    const int bc = blockIdx.x >> 2;
    const int b = bc / DIM;
    const int c = bc % DIM;
    const int t = threadIdx.x;
    const int r0 = tile * TILE_H;

    const int slo = (tile == 0) ? PAD * (WW / 4) : 0;
    const int shi = (tile == NTILE - 1) ? (SROWS - PAD) * (WW / 4) : NSLOT;
    const float* xbase = x + (size_t)bc * HH * WW + (ptrdiff_t)(r0 - PAD) * WW;

#pragma unroll
    for (int i = 0; i < (NSLOT + 255) / 256; ++i) {
        const int s = t + i * 256;
        if (s < NSLOT) {
            int sc = s;
            if (sc < slo) sc = slo;
            if (sc >= shi) sc = shi - 1;
            __builtin_amdgcn_global_load_lds(
                (const __attribute__((address_space(1))) void*)(xbase + (size_t)sc * 4),
                (__attribute__((address_space(3))) void*)((float*)smem + (size_t)s * 4),
                16, 0, 0);
        }
    }

    if (t < HID) y_s[t] = y_glob[b * HID + t];
    __syncthreads();

    if (t < KK) {
        const int o = c * KK + t;
        const float4* w2r = (const float4*)(w2 + (size_t)o * HID);
        float acc = b2[o];
#pragma unroll
        for (int j = 0; j < HID / 4; ++j) {
            float4 wv = w2r[j];
            acc += y_s[4 * j] * wv.x + y_s[4 * j + 1] * wv.y +
                   y_s[4 * j + 2] * wv.z + y_s[4 * j + 3] * wv.w;
        }
        wk_s[t] = acc;
    } else if (t >= 160) {
        const int zi = t - 160;
        if (tile == 0) {
            ((float4*)smem)[zi] = make_float4(0.f, 0.f, 0.f, 0.f);
        } else if (tile == NTILE - 1) {
            ((float4*)smem)[(SROWS - PAD) * (WW / 4) + zi] =
                make_float4(0.f, 0.f, 0.f, 0.f);
        }
    }
    __syncthreads();

    float wreg[KK];
#pragma unroll
    for (int i = 0; i < KK; ++i) wreg[i] = wk_s[i];
    const float bv = bias[c];

    const int c4 = t & 31;
    const int strip = t >> 5;
    const int sbase = strip * RPT;
    float* outp = out + (size_t)bc * HH * WW + (size_t)(r0 + sbase) * WW + c4 * 4;

    float acc[RPT][4];
#pragma unroll
    for (int i = 0; i < RPT; ++i)
        acc[i][0] = acc[i][1] = acc[i][2] = acc[i][3] = 0.f;

#pragma unroll
    for (int ir = 0; ir < RPT + KS - 1; ++ir) {
        const float4* row4 = (const float4*)&smem[sbase + ir][0];
        const float4 f1 = row4[c4];
        float4 f0 = make_float4(0.f, 0.f, 0.f, 0.f);
        float4 f2 = make_float4(0.f, 0.f, 0.f, 0.f);
        if (c4 > 0)  f0 = row4[c4 - 1];
        if (c4 < 31) f2 = row4[c4 + 1];
        const float v[12] = {f0.x, f0.y, f0.z, f0.w,
                             f1.x, f1.y, f1.z, f1.w,
                             f2.x, f2.y, f2.z, f2.w};
#pragma unroll
        for (int ky = 0; ky < KS; ++ky) {
            const int o = ir - ky;
            if (o >= 0 && o < RPT) {
                float* a = acc[o];
#pragma unroll
                for (int kx = 0; kx < KS; ++kx) {
                    const float wv = wreg[ky * KS + kx];
                    a[0] += wv * v[1 + kx];
                    a[1] += wv * v[2 + kx];
                    a[2] += wv * v[3 + kx];
                    a[3] += wv * v[4 + kx];
                }
            }
        }
        if (ir >= KS - 1) {
            float* a = acc[ir - (KS - 1)];
            float4 o4 = make_float4(a[0] + bv, a[1] + bv, a[2] + bv, a[3] + bv);
            *((float4*)(outp + (size_t)(ir - (KS - 1)) * WW)) = o4;
        }
    }
}

extern "C" void kernel_launch(void* const* d_in, const int* in_sizes, int n_in,
                              void* d_out, int out_size, void* d_ws, size_t ws_size,
                              hipStream_t stream) {
    const float* x     = (const float*)d_in[0];
    const float* w1    = (const float*)d_in[1];
    const float* gamma = (const float*)d_in[2];
    const float* beta  = (const float*)d_in[3];
    const float* mean  = (const float*)d_in[4];
    const float* var   = (const float*)d_in[5];
    const float* w2    = (const float*)d_in[6];
    const float* b2    = (const float*)d_in[7];
    const float* bias  = (const float*)d_in[8];
    float* out = (float*)d_out;

    float* pooled = (float*)d_ws;                    // B*DIM floats
    const size_t need = (size_t)BATCH * DIM * sizeof(float)
                      + (size_t)BATCH * DIM * WSTR * sizeof(float);   // ~326 KB

    pool_kernel<<<BATCH * DIM, 256, 0, stream>>>(x, pooled);

    if (ws_size >= need) {
        // hoist path: wdyn precomputed, dwconv prologue is a single load
        float* wdyn = pooled + BATCH * DIM;          // offset 6144 B, 16B-aligned
        wgen_full_kernel<<<BATCH * DIM, 64, 0, stream>>>(
            pooled, w1, gamma, beta, mean, var, w2, b2, wdyn);
        dwconv_hoisted_kernel<<<BATCH * DIM * NTILE, 256, 0, stream>>>(
            x, wdyn, bias, out);
    } else {
        // fallback: exact R12 path (proven 65.5us)
        float* y_glob = pooled + BATCH * DIM;        // 384 floats
        wgen_y_kernel<<<BATCH, 64, 0, stream>>>(
            pooled, w1, gamma, beta, mean, var, y_glob);
        dwconv_fused_kernel<<<BATCH * DIM * NTILE, 256, 0, stream>>>(
            x, y_glob, w2, b2, bias, out);
    }
}

// Round 17
// 226.199 us; speedup vs baseline: 1.6476x; 1.0393x over previous
//
#include <hip/hip_runtime.h>

#define BATCH 8
#define DIM 192
#define HH 128
#define WW 128
#define KS 7
#define PAD 3
#define HID 48
#define KK 49            // KS*KS
#define BN_EPS 1e-5f
#define WSTR 52          // wdyn row stride (floats): 208 B, keeps rows 16B-aligned

#define TILE_H 64
#define SROWS (TILE_H + KS - 1)      // 70
#define NSLOT (SROWS * (WW / 4))     // 2240 float4 slots = 35*64 -> wave-uniform guard ok
#define NTILE (HH / TILE_H)          // 2
#define RPT   8                      // output rows per thread (8 strips x 8 rows)

static_assert(NSLOT % 64 == 0, "staging guard must be wave-uniform");

// ---------------- Kernel A: global average pool over H*W ----------------
__global__ __launch_bounds__(256) void pool_kernel(const float* __restrict__ x,
                                                   float* __restrict__ pooled) {
    const int bc = blockIdx.x;                       // 0..B*DIM-1
    const float4* p = (const float4*)(x + (size_t)bc * HH * WW);
    const int t = threadIdx.x;
    float s = 0.f;
#pragma unroll
    for (int i = 0; i < 16; ++i) {                   // 16384 floats = 4096 float4 / 256 thr
        float4 v = p[t + i * 256];
        s += (v.x + v.y) + (v.z + v.w);
    }
#pragma unroll
    for (int off = 32; off > 0; off >>= 1) s += __shfl_down(s, off, 64);
    __shared__ float wsum[4];
    const int wave = t >> 6, lane = t & 63;
    if (lane == 0) wsum[wave] = s;
    __syncthreads();
    if (t == 0) {
        float tot = (wsum[0] + wsum[1]) + (wsum[2] + wsum[3]);
        pooled[bc] = tot * (1.0f / (HH * WW));
    }
}

// ------------- Kernel A2: full weight-gen per (b,c) (R13-proven) -----------
__global__ __launch_bounds__(64) void wgen_full_kernel(
        const float* __restrict__ pooled,
        const float* __restrict__ w1,
        const float* __restrict__ gamma,
        const float* __restrict__ beta,
        const float* __restrict__ mean,
        const float* __restrict__ var,
        const float* __restrict__ w2,
        const float* __restrict__ b2,
        float* __restrict__ wdyn) {
    __shared__ float y_s[HID];
    const int bc = blockIdx.x;
    const int b = bc / DIM, c = bc % DIM;
    const int t = threadIdx.x;
    if (t < HID) {
        const float4* pr = (const float4*)(pooled + b * DIM);
        const float4* wr = (const float4*)(w1 + (size_t)t * DIM);
        float acc = 0.f;
#pragma unroll
        for (int j = 0; j < DIM / 4; ++j) {
            float4 pv = pr[j], wv = wr[j];
            acc += pv.x * wv.x + pv.y * wv.y + pv.z * wv.z + pv.w * wv.w;
        }
        float yv = (acc - mean[t]) * rsqrtf(var[t] + BN_EPS) * gamma[t] + beta[t];
        y_s[t] = yv > 0.f ? yv : 0.f;
    }
    __syncthreads();
    if (t < KK) {
        const int o = c * KK + t;
        const float4* w2r = (const float4*)(w2 + (size_t)o * HID);
        float acc = b2[o];
#pragma unroll
        for (int j = 0; j < HID / 4; ++j) {
            float4 wv = w2r[j];
            acc += y_s[4 * j] * wv.x + y_s[4 * j + 1] * wv.y +
                   y_s[4 * j + 2] * wv.z + y_s[4 * j + 3] * wv.w;
        }
        wdyn[(size_t)bc * WSTR + t] = acc;
    }
}

// ---------- Kernel B: depthwise 7x7, TILE_H=64/RPT=8, weights preloaded ----
// R14/R15/R16/R17: recombines two harness-proven halves. (1) R0's TILE_H=64
// compute geometry: 14 input rows, acc[7][4] ring, 42 ds_read_b128 per 8
// output rows (vs 60 at RPT=4 -> 30% fewer LDS reads AND conflicts; R12 PMC:
// 8.26M conflict cycles was ~half the LDS time). (2) R13's hoisted-weight
// prologue (one L2-hot row load; stage-1/2 dots moved to wgen_full). Halves
// prologue/barrier count (3072 blocks). LDS 35.8KB -> 4 blocks/CU = same
// VGPR-bound residency as R13 -> no occupancy cost.
// Weights go LDS->VGPR (proven). NO readfirstlane, NO launch-bounds 2nd arg
// (toolchain poison: R1/R2 correctness, R6 spill -- see session journal).
// Staging: async global_load_lds, 16B/lane, wave-uniform dest (m104/m108);
// NSLOT=2240=35*64 -> `s < NSLOT` wave-uniform. Both tiles are edge tiles
// (NTILE=2): clamped out-of-image sources zero-overwritten after the drain
// barrier, then one more barrier (block-uniform condition).
__global__ __launch_bounds__(256) void dwconv_hoisted_kernel(
        const float* __restrict__ x,
        const float* __restrict__ wdyn,
        const float* __restrict__ bias,
        float* __restrict__ out) {
    __shared__ float smem[SROWS][WW];                // 70*128*4 = 35840 B
    __shared__ float wk_s[KK];
    const int tile = blockIdx.x & (NTILE - 1);       // 2 tiles of a channel adjacent
    const int bc = blockIdx.x >> 1;
    const int c = bc % DIM;
    const int t = threadIdx.x;
    const int r0 = tile * TILE_H;

    // ---- issue async staging DMA first ----
    // valid input rows: [r0-3, r0+66] ∩ [0,128)
    const int slo = (tile == 0) ? PAD * (WW / 4) : 0;                       // 96 or 0
    const int shi = (tile == NTILE - 1) ? (SROWS - PAD) * (WW / 4) : NSLOT; // 2144 or 2240
    const float* xbase = x + (size_t)bc * HH * WW + (ptrdiff_t)(r0 - PAD) * WW;

#pragma unroll
    for (int i = 0; i < (NSLOT + 255) / 256; ++i) {  // 9 iters
        const int s = t + i * 256;
        if (s < NSLOT) {                             // wave-uniform (2240 = 35*64)
            int sc = s;                              // clamp SOURCE only (per-lane ok)
            if (sc < slo) sc = slo;
            if (sc >= shi) sc = shi - 1;
            __builtin_amdgcn_global_load_lds(
                (const __attribute__((address_space(1))) void*)(xbase + (size_t)sc * 4),
                (__attribute__((address_space(3))) void*)((float*)smem + (size_t)s * 4),
                16, 0, 0);
        }
    }

    // ---- preloaded weights: one L2-hot row load, overlaps in-flight DMA ----
    if (t < KK) wk_s[t] = wdyn[(size_t)bc * WSTR + t];
    __syncthreads();                                 // DMA drained; wk_s visible

    // ---- zero-fill the 3 out-of-image halo rows (both tiles are edges) ----
    if (t < 96) {
        const int zslot = (tile ? (SROWS - PAD) * (WW / 4) : 0) + t;
        ((float4*)smem)[zslot] = make_float4(0.f, 0.f, 0.f, 0.f);
    }
    __syncthreads();

    // ---- weights in VGPRs (proven form) ----
    float wreg[KK];
#pragma unroll
    for (int i = 0; i < KK; ++i) wreg[i] = wk_s[i];
    const float bv = bias[c];

    // ---- compute: 8 strips x 8 rows, sliding ring over 14 input rows ----
    // (R0's verified loop: acc[7][4] ring, store+reset at ir>=6)
    const int c4 = t & 31;                           // 4-col group
    const int strip = t >> 5;                        // 0..7
    const int sbase = strip * RPT;
    float* outp = out + (size_t)bc * HH * WW + (size_t)(r0 + sbase) * WW + c4 * 4;

    float acc[7][4];
#pragma unroll
    for (int i = 0; i < 7; ++i)
        acc[i][0] = acc[i][1] = acc[i][2] = acc[i][3] = 0.f;

#pragma unroll
    for (int ir = 0; ir < RPT + KS - 1; ++ir) {      // 14 input rows
        const float4* row4 = (const float4*)&smem[sbase + ir][0];
        const float4 f1 = row4[c4];
        float4 f0 = make_float4(0.f, 0.f, 0.f, 0.f);
        float4 f2 = make_float4(0.f, 0.f, 0.f, 0.f);
        if (c4 > 0)  f0 = row4[c4 - 1];              // cols -4..-1 (zero at left edge)
        if (c4 < 31) f2 = row4[c4 + 1];              // cols +4..+7 (zero at right edge)
        const float v[12] = {f0.x, f0.y, f0.z, f0.w,
                             f1.x, f1.y, f1.z, f1.w,
                             f2.x, f2.y, f2.z, f2.w};
#pragma unroll
        for (int ky = 0; ky < KS; ++ky) {
            const int o = ir - ky;                   // pending output row (compile-time)
            if (o >= 0 && o < RPT) {
                float* a = acc[o % 7];
#pragma unroll
                for (int kx = 0; kx < KS; ++kx) {
                    const float wv = wreg[ky * KS + kx];
                    a[0] += wv * v[1 + kx];
                    a[1] += wv * v[2 + kx];
                    a[2] += wv * v[3 + kx];
                    a[3] += wv * v[4 + kx];
                }
            }
        }
        if (ir >= KS - 1) {                          // output row ir-6 complete
            float* a = acc[(ir - (KS - 1)) % 7];
            float4 o4 = make_float4(a[0] + bv, a[1] + bv, a[2] + bv, a[3] + bv);
            *((float4*)(outp + (size_t)(ir - (KS - 1)) * WW)) = o4;
            a[0] = a[1] = a[2] = a[3] = 0.f;         // free ring slot
        }
    }
}

extern "C" void kernel_launch(void* const* d_in, const int* in_sizes, int n_in,
                              void* d_out, int out_size, void* d_ws, size_t ws_size,
                              hipStream_t stream) {
    const float* x     = (const float*)d_in[0];
    const float* w1    = (const float*)d_in[1];
    const float* gamma = (const float*)d_in[2];
    const float* beta  = (const float*)d_in[3];
    const float* mean  = (const float*)d_in[4];
    const float* var   = (const float*)d_in[5];
    const float* w2    = (const float*)d_in[6];
    const float* b2    = (const float*)d_in[7];
    const float* bias  = (const float*)d_in[8];
    float* out = (float*)d_out;

    // workspace: pooled [1536] | wdyn [1536][52] ~= 326 KB
    // (R13 confirmed ws_size suffices: hoist path ran -- dwconv < 58us,
    //  fallback's 65.5 would have shown in top-5)
    float* pooled = (float*)d_ws;
    float* wdyn   = pooled + BATCH * DIM;            // offset 6144 B, 16B-aligned

    pool_kernel<<<BATCH * DIM, 256, 0, stream>>>(x, pooled);
    wgen_full_kernel<<<BATCH * DIM, 64, 0, stream>>>(
        pooled, w1, gamma, beta, mean, var, w2, b2, wdyn);
    dwconv_hoisted_kernel<<<BATCH * DIM * NTILE, 256, 0, stream>>>(
        x, wdyn, bias, out);
}

// Round 18
// 222.521 us; speedup vs baseline: 1.6748x; 1.0165x over previous
//
#include <hip/hip_runtime.h>

#define BATCH 8
#define DIM 192
#define HH 128
#define WW 128
#define KS 7
#define PAD 3
#define HID 48
#define KK 49            // KS*KS
#define BN_EPS 1e-5f
#define WSTR 52          // wdyn row stride (floats): 208 B = 13 float4 exactly

#define BAND_H 16                     // output rows per wave (2 strips x 8)
#define SROWS (BAND_H + KS - 1)       // 22 input rows incl. halo
#define NSLOT (SROWS * (WW / 4))      // 704 float4 slots = 11*64 -> all lanes active
#define NBAND (HH / BAND_H)           // 8
#define RPT   8                       // output rows per thread

static_assert(NSLOT % 64 == 0, "staging must keep all 64 lanes active");

// ---------------- Kernel A: global average pool over H*W ----------------
__global__ __launch_bounds__(256) void pool_kernel(const float* __restrict__ x,
                                                   float* __restrict__ pooled) {
    const int bc = blockIdx.x;                       // 0..B*DIM-1
    const float4* p = (const float4*)(x + (size_t)bc * HH * WW);
    const int t = threadIdx.x;
    float s = 0.f;
#pragma unroll
    for (int i = 0; i < 16; ++i) {                   // 16384 floats = 4096 float4 / 256 thr
        float4 v = p[t + i * 256];
        s += (v.x + v.y) + (v.z + v.w);
    }
#pragma unroll
    for (int off = 32; off > 0; off >>= 1) s += __shfl_down(s, off, 64);
    __shared__ float wsum[4];
    const int wave = t >> 6, lane = t & 63;
    if (lane == 0) wsum[wave] = s;
    __syncthreads();
    if (t == 0) {
        float tot = (wsum[0] + wsum[1]) + (wsum[2] + wsum[3]);
        pooled[bc] = tot * (1.0f / (HH * WW));
    }
}

// ------------- Kernel A2: full weight-gen per (b,c) (R13/R17-proven) -------
__global__ __launch_bounds__(64) void wgen_full_kernel(
        const float* __restrict__ pooled,
        const float* __restrict__ w1,
        const float* __restrict__ gamma,
        const float* __restrict__ beta,
        const float* __restrict__ mean,
        const float* __restrict__ var,
        const float* __restrict__ w2,
        const float* __restrict__ b2,
        float* __restrict__ wdyn) {
    __shared__ float y_s[HID];
    const int bc = blockIdx.x;
    const int b = bc / DIM, c = bc % DIM;
    const int t = threadIdx.x;
    if (t < HID) {
        const float4* pr = (const float4*)(pooled + b * DIM);
        const float4* wr = (const float4*)(w1 + (size_t)t * DIM);
        float acc = 0.f;
#pragma unroll
        for (int j = 0; j < DIM / 4; ++j) {
            float4 pv = pr[j], wv = wr[j];
            acc += pv.x * wv.x + pv.y * wv.y + pv.z * wv.z + pv.w * wv.w;
        }
        float yv = (acc - mean[t]) * rsqrtf(var[t] + BN_EPS) * gamma[t] + beta[t];
        y_s[t] = yv > 0.f ? yv : 0.f;
    }
    __syncthreads();
    if (t < KK) {
        const int o = c * KK + t;
        const float4* w2r = (const float4*)(w2 + (size_t)o * HID);
        float acc = b2[o];
#pragma unroll
        for (int j = 0; j < HID / 4; ++j) {
            float4 wv = w2r[j];
            acc += y_s[4 * j] * wv.x + y_s[4 * j + 1] * wv.y +
                   y_s[4 * j + 2] * wv.z + y_s[4 * j + 3] * wv.w;
        }
        wdyn[(size_t)bc * WSTR + t] = acc;
    }
}

// ---------- Kernel B: depthwise 7x7, one independent WAVE per 16-row band --
// R18: barrier-free restructure. Insight from R17's counters: with strip-
// per-lane-group assignment no LDS data crosses waves -- the barrier only
// existed because staging slots were block-linear. Now each 64-thread block
// (one wave) owns a 16-row output band + its private 22-row LDS window:
//   * staging: 11 global_load_lds, all 64 lanes active (704 = 11*64), no
//     guard, wave-uniform dest (m104/m108), same clamp math as R17.
//   * weights: 13 float4 per-lane direct global->VGPR (L2-hot; issued FIRST
//     so the compiler's auto-vmcnt for the unpack leaves the 11 DMAs in
//     flight underneath).
//   * one explicit s_waitcnt vmcnt(0) (memory clobber; ds ops are memory
//     ops so the rule-18 register-hoist trap doesn't apply) replaces
//     __syncthreads. Zero-fill of edge halos is same-wave ds_write before
//     may-aliasing ds_read -> ordered by the compiler.
//   * compute: R17's verified acc[7][4] ring, verbatim (strip = t>>5 now
//     spans 2 strips/wave).
// Every wave is an independent pipeline -> block-lockstep stalls decorrelate
// structurally; 14 blocks/CU by LDS (11.3 KB) under the 16-wave VGPR cap.
// NO readfirstlane, NO launch-bounds 2nd arg (toolchain poison: R1/R2
// correctness, R6 spill). Falsifier: VGPR > 128 -> 8 waves/CU -> regression.
__global__ __launch_bounds__(64) void dwconv_wave_kernel(
        const float* __restrict__ x,
        const float* __restrict__ wdyn,
        const float* __restrict__ bias,
        float* __restrict__ out) {
    __shared__ float smem[SROWS][WW];                // 22*128*4 = 11264 B
    const int band = blockIdx.x & (NBAND - 1);       // 8 bands of a channel adjacent
    const int bc = blockIdx.x >> 3;
    const int c = bc % DIM;
    const int t = threadIdx.x;                       // 0..63
    const int r0 = band * BAND_H;

    // ---- weights first (13 float4 -> in flight), then staging DMA ----
    const float4* wrow = (const float4*)(wdyn + (size_t)bc * WSTR);
    float4 w4[13];
#pragma unroll
    for (int i = 0; i < 13; ++i) w4[i] = wrow[i];    // floats 48..51: 1 real + 3 pad

    // valid input rows: [r0-3, r0+18] ∩ [0,128)
    const int slo = (band == 0) ? PAD * (WW / 4) : 0;                        // 96 or 0
    const int shi = (band == NBAND - 1) ? (SROWS - PAD) * (WW / 4) : NSLOT;  // 608 or 704
    const float* xbase = x + (size_t)bc * HH * WW + (ptrdiff_t)(r0 - PAD) * WW;

#pragma unroll
    for (int i = 0; i < NSLOT / 64; ++i) {           // 11 iters, no guard needed
        const int s = t + i * 64;
        int sc = s;                                  // clamp SOURCE only (per-lane ok)
        if (sc < slo) sc = slo;
        if (sc >= shi) sc = shi - 1;
        __builtin_amdgcn_global_load_lds(
            (const __attribute__((address_space(1))) void*)(xbase + (size_t)sc * 4),
            (__attribute__((address_space(3))) void*)((float*)smem + (size_t)s * 4),
            16, 0, 0);
    }

    // ---- unpack weights (compiler waits only for w4: vmcnt(11), DMA flies) ----
    float wreg[KK];
#pragma unroll
    for (int i = 0; i < 12; ++i) {
        wreg[4 * i + 0] = w4[i].x;
        wreg[4 * i + 1] = w4[i].y;
        wreg[4 * i + 2] = w4[i].z;
        wreg[4 * i + 3] = w4[i].w;
    }
    wreg[48] = w4[12].x;
    const float bv = bias[c];

    // ---- drain the staging DMA (replaces __syncthreads: wave-private LDS) ----
    asm volatile("s_waitcnt vmcnt(0)" ::: "memory");

    // ---- zero-fill the 3 out-of-image halo rows (edge bands only) ----
    if (band == 0) {                                 // slots 0..95
        ((float4*)smem)[t] = make_float4(0.f, 0.f, 0.f, 0.f);
        if (t < 32) ((float4*)smem)[64 + t] = make_float4(0.f, 0.f, 0.f, 0.f);
    } else if (band == NBAND - 1) {                  // slots 608..703
        ((float4*)smem)[608 + t] = make_float4(0.f, 0.f, 0.f, 0.f);
        if (t < 32) ((float4*)smem)[672 + t] = make_float4(0.f, 0.f, 0.f, 0.f);
    }
    // same-wave ds_write -> may-aliasing ds_read below: compiler-ordered.

    // ---- compute: 2 strips x 8 rows, sliding ring over 14 input rows ----
    const int c4 = t & 31;                           // 4-col group
    const int strip = t >> 5;                        // 0..1
    const int sbase = strip * RPT;                   // LDS row base (0 or 8)
    float* outp = out + (size_t)bc * HH * WW + (size_t)(r0 + sbase) * WW + c4 * 4;

    float acc[7][4];
#pragma unroll
    for (int i = 0; i < 7; ++i)
        acc[i][0] = acc[i][1] = acc[i][2] = acc[i][3] = 0.f;

#pragma unroll
    for (int ir = 0; ir < RPT + KS - 1; ++ir) {      // 14 input rows
        const float4* row4 = (const float4*)&smem[sbase + ir][0];
        const float4 f1 = row4[c4];
        float4 f0 = make_float4(0.f, 0.f, 0.f, 0.f);
        float4 f2 = make_float4(0.f, 0.f, 0.f, 0.f);
        if (c4 > 0)  f0 = row4[c4 - 1];              // cols -4..-1 (zero at left edge)
        if (c4 < 31) f2 = row4[c4 + 1];              // cols +4..+7 (zero at right edge)
        const float v[12] = {f0.x, f0.y, f0.z, f0.w,
                             f1.x, f1.y, f1.z, f1.w,
                             f2.x, f2.y, f2.z, f2.w};
#pragma unroll
        for (int ky = 0; ky < KS; ++ky) {
            const int o = ir - ky;                   // pending output row (compile-time)
            if (o >= 0 && o < RPT) {
                float* a = acc[o % 7];
#pragma unroll
                for (int kx = 0; kx < KS; ++kx) {
                    const float wv = wreg[ky * KS + kx];
                    a[0] += wv * v[1 + kx];
                    a[1] += wv * v[2 + kx];
                    a[2] += wv * v[3 + kx];
                    a[3] += wv * v[4 + kx];
                }
            }
        }
        if (ir >= KS - 1) {                          // output row ir-6 complete
            float* a = acc[(ir - (KS - 1)) % 7];
            float4 o4 = make_float4(a[0] + bv, a[1] + bv, a[2] + bv, a[3] + bv);
            *((float4*)(outp + (size_t)(ir - (KS - 1)) * WW)) = o4;
            a[0] = a[1] = a[2] = a[3] = 0.f;         // free ring slot
        }
    }
}

extern "C" void kernel_launch(void* const* d_in, const int* in_sizes, int n_in,
                              void* d_out, int out_size, void* d_ws, size_t ws_size,
                              hipStream_t stream) {
    const float* x     = (const float*)d_in[0];
    const float* w1    = (const float*)d_in[1];
    const float* gamma = (const float*)d_in[2];
    const float* beta  = (const float*)d_in[3];
    const float* mean  = (const float*)d_in[4];
    const float* var   = (const float*)d_in[5];
    const float* w2    = (const float*)d_in[6];
    const float* b2    = (const float*)d_in[7];
    const float* bias  = (const float*)d_in[8];
    float* out = (float*)d_out;

    // workspace: pooled [1536] | wdyn [1536][52] ~= 326 KB (R13/R17-proven)
    float* pooled = (float*)d_ws;
    float* wdyn   = pooled + BATCH * DIM;            // offset 6144 B, 16B-aligned

    pool_kernel<<<BATCH * DIM, 256, 0, stream>>>(x, pooled);
    wgen_full_kernel<<<BATCH * DIM, 64, 0, stream>>>(
        pooled, w1, gamma, beta, mean, var, w2, b2, wdyn);
    dwconv_wave_kernel<<<BATCH * DIM * NBAND, 64, 0, stream>>>(
        x, wdyn, bias, out);
}